// Round 1
// baseline (269.413 us; speedup 1.0000x reference)
//
#include <hip/hip_runtime.h>
#include <math.h>

#define BATCH 4096
#define NPTS  2048
#define THREADS 256

// accumulate one point: h[c*3+d] += src_c * (m * tgt_d)
#define ACC(sx, sy, sz, tx, ty, tz, mm) do {                                   \
    float d0 = (mm) * (tx), d1 = (mm) * (ty), d2 = (mm) * (tz);                \
    h[0] = fmaf((sx), d0, h[0]); h[1] = fmaf((sx), d1, h[1]); h[2] = fmaf((sx), d2, h[2]); \
    h[3] = fmaf((sy), d0, h[3]); h[4] = fmaf((sy), d1, h[4]); h[5] = fmaf((sy), d2, h[5]); \
    h[6] = fmaf((sz), d0, h[6]); h[7] = fmaf((sz), d1, h[7]); h[8] = fmaf((sz), d2, h[8]); \
} while (0)

__global__ __launch_bounds__(THREADS)
void svdhead_kernel(const float* __restrict__ src, const float* __restrict__ tgt,
                    const float* __restrict__ mask, float* __restrict__ out)
{
    const int b = blockIdx.x;
    const float4* s4 = (const float4*)(src  + (size_t)b * (NPTS * 3));
    const float4* t4 = (const float4*)(tgt  + (size_t)b * (NPTS * 3));
    const float4* m4 = (const float4*)(mask + (size_t)b * NPTS);

    float h[9] = {0.f, 0.f, 0.f, 0.f, 0.f, 0.f, 0.f, 0.f, 0.f};

    // 4 points per group; NPTS/4 = 512 groups; 2 iterations per thread
    for (int g = threadIdx.x; g < NPTS / 4; g += THREADS) {
        float4 m  = m4[g];
        float4 sa = s4[3 * g + 0], sb = s4[3 * g + 1], sc = s4[3 * g + 2];
        float4 ta = t4[3 * g + 0], tb = t4[3 * g + 1], tc = t4[3 * g + 2];
        ACC(sa.x, sa.y, sa.z, ta.x, ta.y, ta.z, m.x);
        ACC(sa.w, sb.x, sb.y, ta.w, tb.x, tb.y, m.y);
        ACC(sb.z, sb.w, sc.x, tb.z, tb.w, tc.x, m.z);
        ACC(sc.y, sc.z, sc.w, tc.y, tc.z, tc.w, m.w);
    }

    // wave-64 reduction of 9 accumulators
#pragma unroll
    for (int off = 32; off > 0; off >>= 1) {
#pragma unroll
        for (int i = 0; i < 9; ++i) h[i] += __shfl_down(h[i], off);
    }

    __shared__ float sh[THREADS / 64][9];
    const int wid  = threadIdx.x >> 6;
    const int lane = threadIdx.x & 63;
    if (lane == 0) {
#pragma unroll
        for (int i = 0; i < 9; ++i) sh[wid][i] = h[i];
    }
    __syncthreads();

    if (threadIdx.x == 0) {
        // final cross-wave sum -> H (fp64 from here on)
        double H[3][3];
#pragma unroll
        for (int i = 0; i < 9; ++i) {
            double v = (double)sh[0][i] + (double)sh[1][i] +
                       (double)sh[2][i] + (double)sh[3][i];
            H[i / 3][i % 3] = v;
        }

        // A = H^T H (symmetric)
        double A[3][3];
#pragma unroll
        for (int i = 0; i < 3; ++i)
#pragma unroll
            for (int j = 0; j < 3; ++j)
                A[i][j] = H[0][i] * H[0][j] + H[1][i] * H[1][j] + H[2][i] * H[2][j];

        double V[3][3] = {{1, 0, 0}, {0, 1, 0}, {0, 0, 1}};

        // cyclic Jacobi, 8 sweeps (fp64, converges cubically; overkill on purpose)
        const int pq[3][3] = {{0, 1, 2}, {0, 2, 1}, {1, 2, 0}};
        for (int sweep = 0; sweep < 8; ++sweep) {
            for (int r = 0; r < 3; ++r) {
                const int p = pq[r][0], q = pq[r][1], k = pq[r][2];
                double apq = A[p][q];
                if (fabs(apq) > 1e-300) {
                    double theta = (A[q][q] - A[p][p]) / (2.0 * apq);
                    double t = 1.0 / (fabs(theta) + sqrt(theta * theta + 1.0));
                    if (theta < 0.0) t = -t;
                    double c = 1.0 / sqrt(t * t + 1.0);
                    double s = t * c;
                    double app = A[p][p], aqq = A[q][q];
                    A[p][p] = app - t * apq;
                    A[q][q] = aqq + t * apq;
                    A[p][q] = A[q][p] = 0.0;
                    double akp = A[k][p], akq = A[k][q];
                    A[k][p] = A[p][k] = c * akp - s * akq;
                    A[k][q] = A[q][k] = s * akp + c * akq;
#pragma unroll
                    for (int i = 0; i < 3; ++i) {
                        double vip = V[i][p], viq = V[i][q];
                        V[i][p] = c * vip - s * viq;
                        V[i][q] = s * vip + c * viq;
                    }
                }
            }
        }

        // order eigenvalues descending: need top-2 eigenvectors
        int i0 = 0;
        if (A[1][1] > A[i0][i0]) i0 = 1;
        if (A[2][2] > A[i0][i0]) i0 = 2;
        const int ca = (i0 + 1) % 3, cb = (i0 + 2) % 3;
        const int i1 = (A[ca][ca] >= A[cb][cb]) ? ca : cb;

        double v0[3], v1[3];
#pragma unroll
        for (int i = 0; i < 3; ++i) { v0[i] = V[i][i0]; v1[i] = V[i][i1]; }

        // u0 = norm(H v0); u1 = norm(GS(H v1)); u2 = u0 x u1; v2 = v0 x v1
        double b0[3], b1[3];
#pragma unroll
        for (int r = 0; r < 3; ++r) {
            b0[r] = H[r][0] * v0[0] + H[r][1] * v0[1] + H[r][2] * v0[2];
            b1[r] = H[r][0] * v1[0] + H[r][1] * v1[1] + H[r][2] * v1[2];
        }
        double n0 = b0[0] * b0[0] + b0[1] * b0[1] + b0[2] * b0[2];
        double inv0 = 1.0 / sqrt(fmax(n0, 1e-300));
        double u0[3] = {b0[0] * inv0, b0[1] * inv0, b0[2] * inv0};
        double d01 = u0[0] * b1[0] + u0[1] * b1[1] + u0[2] * b1[2];
        double w[3] = {b1[0] - d01 * u0[0], b1[1] - d01 * u0[1], b1[2] - d01 * u0[2]};
        double nw = w[0] * w[0] + w[1] * w[1] + w[2] * w[2];
        double inv1 = 1.0 / sqrt(fmax(nw, 1e-300));
        double u1[3] = {w[0] * inv1, w[1] * inv1, w[2] * inv1};
        double u2[3] = {u0[1] * u1[2] - u0[2] * u1[1],
                        u0[2] * u1[0] - u0[0] * u1[2],
                        u0[0] * u1[1] - u0[1] * u1[0]};
        double v2[3] = {v0[1] * v1[2] - v0[2] * v1[1],
                        v0[2] * v1[0] - v0[0] * v1[2],
                        v0[0] * v1[1] - v0[1] * v1[0]};

        // R = v0 u0^T + v1 u1^T + v2 u2^T  (== V diag(1,1,sign det) U^T, Kabsch)
        float* o = out + (size_t)b * 9;
#pragma unroll
        for (int r = 0; r < 3; ++r)
#pragma unroll
            for (int c = 0; c < 3; ++c)
                o[r * 3 + c] = (float)(v0[r] * u0[c] + v1[r] * u1[c] + v2[r] * u2[c]);
    }
}

extern "C" void kernel_launch(void* const* d_in, const int* in_sizes, int n_in,
                              void* d_out, int out_size, void* d_ws, size_t ws_size,
                              hipStream_t stream) {
    const float* src  = (const float*)d_in[0];
    const float* tgt  = (const float*)d_in[1];
    // d_in[2] (kpt_src_mask) is unused by the reference
    const float* mask = (const float*)d_in[3];
    float* out = (float*)d_out;

    svdhead_kernel<<<BATCH, THREADS, 0, stream>>>(src, tgt, mask, out);
}

// Round 2
// 262.776 us; speedup vs baseline: 1.0253x; 1.0253x over previous
//
#include <hip/hip_runtime.h>
#include <math.h>

#define BATCH 4096
#define NPTS  2048
#define THREADS 256

// accumulate one point: h[c*3+d] += src_c * (m * tgt_d)
#define ACC(sx, sy, sz, tx, ty, tz, mm) do {                                   \
    float d0 = (mm) * (tx), d1 = (mm) * (ty), d2 = (mm) * (tz);                \
    h[0] = fmaf((sx), d0, h[0]); h[1] = fmaf((sx), d1, h[1]); h[2] = fmaf((sx), d2, h[2]); \
    h[3] = fmaf((sy), d0, h[3]); h[4] = fmaf((sy), d1, h[4]); h[5] = fmaf((sy), d2, h[5]); \
    h[6] = fmaf((sz), d0, h[6]); h[7] = fmaf((sz), d1, h[7]); h[8] = fmaf((sz), d2, h[8]); \
} while (0)

// Kernel 1: H[b] = src^T diag(mask) tgt  -> d_ws (9 floats per batch).
// Pure streaming; no serial tail, blocks retire as soon as the reduce is done.
__global__ __launch_bounds__(THREADS)
void reduce_kernel(const float* __restrict__ src, const float* __restrict__ tgt,
                   const float* __restrict__ mask, float* __restrict__ Hout)
{
    const int b = blockIdx.x;
    const float4* s4 = (const float4*)(src  + (size_t)b * (NPTS * 3));
    const float4* t4 = (const float4*)(tgt  + (size_t)b * (NPTS * 3));
    const float4* m4 = (const float4*)(mask + (size_t)b * NPTS);

    float h[9] = {0.f, 0.f, 0.f, 0.f, 0.f, 0.f, 0.f, 0.f, 0.f};

    // 4 points per group; NPTS/4 = 512 groups; 2 iterations per thread
    for (int g = threadIdx.x; g < NPTS / 4; g += THREADS) {
        float4 m  = m4[g];
        float4 sa = s4[3 * g + 0], sb = s4[3 * g + 1], sc = s4[3 * g + 2];
        float4 ta = t4[3 * g + 0], tb = t4[3 * g + 1], tc = t4[3 * g + 2];
        ACC(sa.x, sa.y, sa.z, ta.x, ta.y, ta.z, m.x);
        ACC(sa.w, sb.x, sb.y, ta.w, tb.x, tb.y, m.y);
        ACC(sb.z, sb.w, sc.x, tb.z, tb.w, tc.x, m.z);
        ACC(sc.y, sc.z, sc.w, tc.y, tc.z, tc.w, m.w);
    }

    // wave-64 butterfly reduction of the 9 accumulators
#pragma unroll
    for (int off = 32; off > 0; off >>= 1) {
#pragma unroll
        for (int i = 0; i < 9; ++i) h[i] += __shfl_down(h[i], off);
    }

    __shared__ float sh[THREADS / 64][9];
    const int wid  = threadIdx.x >> 6;
    const int lane = threadIdx.x & 63;
    if (lane == 0) {
#pragma unroll
        for (int i = 0; i < 9; ++i) sh[wid][i] = h[i];
    }
    __syncthreads();

    // 9 threads write the 9 entries (coalesced-ish; tiny anyway)
    if (threadIdx.x < 9) {
        const int i = threadIdx.x;
        Hout[(size_t)b * 9 + i] = sh[0][i] + sh[1][i] + sh[2][i] + sh[3][i];
    }
}

// Kernel 2: one thread per batch — fp64 Jacobi eigensolve of H^T H + Kabsch
// rotation via cross-product-completed bases (handles the det<0 reflection
// implicitly). 4096 independent solves run concurrently chip-wide.
__global__ __launch_bounds__(THREADS)
void solve_kernel(const float* __restrict__ Hin, float* __restrict__ out)
{
    const int b = blockIdx.x * THREADS + threadIdx.x;
    if (b >= BATCH) return;

    double H[3][3];
#pragma unroll
    for (int i = 0; i < 9; ++i)
        H[i / 3][i % 3] = (double)Hin[(size_t)b * 9 + i];

    // A = H^T H (symmetric)
    double A[3][3];
#pragma unroll
    for (int i = 0; i < 3; ++i)
#pragma unroll
        for (int j = 0; j < 3; ++j)
            A[i][j] = H[0][i] * H[0][j] + H[1][i] * H[1][j] + H[2][i] * H[2][j];

    double V[3][3] = {{1, 0, 0}, {0, 1, 0}, {0, 0, 1}};

    // cyclic Jacobi, 6 sweeps (fp64; cubic convergence — plenty)
    const int pq[3][3] = {{0, 1, 2}, {0, 2, 1}, {1, 2, 0}};
    for (int sweep = 0; sweep < 6; ++sweep) {
        for (int r = 0; r < 3; ++r) {
            const int p = pq[r][0], q = pq[r][1], k = pq[r][2];
            double apq = A[p][q];
            if (fabs(apq) > 1e-300) {
                double theta = (A[q][q] - A[p][p]) / (2.0 * apq);
                double t = 1.0 / (fabs(theta) + sqrt(theta * theta + 1.0));
                if (theta < 0.0) t = -t;
                double c = 1.0 / sqrt(t * t + 1.0);
                double s = t * c;
                double app = A[p][p], aqq = A[q][q];
                A[p][p] = app - t * apq;
                A[q][q] = aqq + t * apq;
                A[p][q] = A[q][p] = 0.0;
                double akp = A[k][p], akq = A[k][q];
                A[k][p] = A[p][k] = c * akp - s * akq;
                A[k][q] = A[q][k] = s * akp + c * akq;
#pragma unroll
                for (int i = 0; i < 3; ++i) {
                    double vip = V[i][p], viq = V[i][q];
                    V[i][p] = c * vip - s * viq;
                    V[i][q] = s * vip + c * viq;
                }
            }
        }
    }

    // order eigenvalues descending: need top-2 eigenvectors
    int i0 = 0;
    if (A[1][1] > A[i0][i0]) i0 = 1;
    if (A[2][2] > A[i0][i0]) i0 = 2;
    const int ca = (i0 + 1) % 3, cb = (i0 + 2) % 3;
    const int i1 = (A[ca][ca] >= A[cb][cb]) ? ca : cb;

    double v0[3], v1[3];
#pragma unroll
    for (int i = 0; i < 3; ++i) { v0[i] = V[i][i0]; v1[i] = V[i][i1]; }

    // u0 = norm(H v0); u1 = norm(GS(H v1)); u2 = u0 x u1; v2 = v0 x v1
    double b0[3], b1[3];
#pragma unroll
    for (int r = 0; r < 3; ++r) {
        b0[r] = H[r][0] * v0[0] + H[r][1] * v0[1] + H[r][2] * v0[2];
        b1[r] = H[r][0] * v1[0] + H[r][1] * v1[1] + H[r][2] * v1[2];
    }
    double n0 = b0[0] * b0[0] + b0[1] * b0[1] + b0[2] * b0[2];
    double inv0 = 1.0 / sqrt(fmax(n0, 1e-300));
    double u0[3] = {b0[0] * inv0, b0[1] * inv0, b0[2] * inv0};
    double d01 = u0[0] * b1[0] + u0[1] * b1[1] + u0[2] * b1[2];
    double w[3] = {b1[0] - d01 * u0[0], b1[1] - d01 * u0[1], b1[2] - d01 * u0[2]};
    double nw = w[0] * w[0] + w[1] * w[1] + w[2] * w[2];
    double inv1 = 1.0 / sqrt(fmax(nw, 1e-300));
    double u1[3] = {w[0] * inv1, w[1] * inv1, w[2] * inv1};
    double u2[3] = {u0[1] * u1[2] - u0[2] * u1[1],
                    u0[2] * u1[0] - u0[0] * u1[2],
                    u0[0] * u1[1] - u0[1] * u1[0]};
    double v2[3] = {v0[1] * v1[2] - v0[2] * v1[1],
                    v0[2] * v1[0] - v0[0] * v1[2],
                    v0[0] * v1[1] - v0[1] * v1[0]};

    // R = v0 u0^T + v1 u1^T + v2 u2^T  (== V diag(1,1,sign det) U^T, Kabsch)
    float* o = out + (size_t)b * 9;
#pragma unroll
    for (int r = 0; r < 3; ++r)
#pragma unroll
        for (int c = 0; c < 3; ++c)
            o[r * 3 + c] = (float)(v0[r] * u0[c] + v1[r] * u1[c] + v2[r] * u2[c]);
}

extern "C" void kernel_launch(void* const* d_in, const int* in_sizes, int n_in,
                              void* d_out, int out_size, void* d_ws, size_t ws_size,
                              hipStream_t stream) {
    const float* src  = (const float*)d_in[0];
    const float* tgt  = (const float*)d_in[1];
    // d_in[2] (kpt_src_mask) is unused by the reference
    const float* mask = (const float*)d_in[3];
    float* out = (float*)d_out;
    float* Hws = (float*)d_ws;   // 4096 * 9 floats = 147 KB, fully overwritten by reduce_kernel

    reduce_kernel<<<BATCH, THREADS, 0, stream>>>(src, tgt, mask, Hws);
    solve_kernel<<<(BATCH + THREADS - 1) / THREADS, THREADS, 0, stream>>>(Hws, out);
}